// Round 6
// baseline (290.419 us; speedup 1.0000x reference)
//
#include <hip/hip_runtime.h>
#include <math.h>

#define Bn 4
#define Cn 64
#define Ln 4096
#define CQ 16
#define NH 4
#define NB 32
#define EPSV 1e-5f

#define MAXS 384    // max bucket size (mean 128, sigma ~11 -> 23 sigma headroom)
#define CH2 48      // staged key chunk (keeps LDS < 20 KB for 8 blocks/CU)
#define QS 4        // query-slice blocks per bucket (interleaved assignment)

#define KSTR 20     // ks row stride (floats)
#define VSTR 64     // vs row stride (floats)

#define QSZ   (Bn*Ln*CQ)      // 262144 floats
#define VSZ   (Bn*Ln*Cn)      // 1048576 floats
#define ACCSZ (Bn*Ln*Cn)

// layout: [q][k][v][acc (x1 or x4)][ssum][ssq];  y overlays q (dead after attn)
#define OFF_K   QSZ
#define OFF_V   (2*QSZ)
#define OFF_ACC (2*QSZ + VSZ)

#define LOG2E 1.44269504088896f

__global__ __launch_bounds__(256) void proj_kernel(
        const float* __restrict__ x,
        const float* __restrict__ Wq, const float* __restrict__ bq,
        const float* __restrict__ Wk, const float* __restrict__ bk,
        const float* __restrict__ Wv, const float* __restrict__ bv,
        float* __restrict__ q, float* __restrict__ k, float* __restrict__ v) {
    __shared__ float sWt[Cn*96];   // [c][r]: rows 0-15 Wq, 16-31 Wk, 32-95 Wv
    __shared__ float sb[96];
    int tid = threadIdx.x;
    for (int idx = tid; idx < Cn*96; idx += 256) {
        int r = idx % 96, c = idx / 96;
        float w;
        if (r < 16)      w = Wq[r*Cn + c];
        else if (r < 32) w = Wk[(r-16)*Cn + c];
        else             w = Wv[(r-32)*Cn + c];
        sWt[c*96 + r] = w;
    }
    if (tid < 96) sb[tid] = (tid < 16) ? bq[tid] : (tid < 32 ? bk[tid-16] : bv[tid-32]);
    __syncthreads();
    int p = tid & 63, og = tid >> 6;       // og uniform per wave
    int gp = blockIdx.x * 64 + p;          // flattened position b*L + l
    int b = gp >> 12, l = gp & (Ln - 1);
    const float* xp = &x[b*Cn*Ln + l];
    int r0 = og * 24;
    float val[24];
    #pragma unroll
    for (int i = 0; i < 24; i++) val[i] = sb[r0 + i];
    #pragma unroll
    for (int c0 = 0; c0 < Cn; c0 += 8) {
        float xv[8];
        #pragma unroll
        for (int i = 0; i < 8; i++) xv[i] = xp[(c0 + i)*Ln];   // coalesced in p
        #pragma unroll
        for (int i = 0; i < 8; i++) {
            const float* wrow = &sWt[(c0 + i)*96 + r0];        // LDS broadcast
            #pragma unroll
            for (int j = 0; j < 24; j++) val[j] = fmaf(wrow[j], xv[i], val[j]);
        }
    }
    float4* q4 = (float4*)&q[gp*CQ];
    float4* k4 = (float4*)&k[gp*CQ];
    float4* v4 = (float4*)&v[gp*Cn];
    float4 vv[6];
    #pragma unroll
    for (int i = 0; i < 6; i++)
        vv[i] = make_float4(val[4*i], val[4*i+1], val[4*i+2], val[4*i+3]);
    if (og == 0) {
        q4[0]=vv[0]; q4[1]=vv[1]; q4[2]=vv[2]; q4[3]=vv[3];
        k4[0]=vv[4]; k4[1]=vv[5];
    } else if (og == 1) {
        k4[2]=vv[0]; k4[3]=vv[1];
        v4[0]=vv[2]; v4[1]=vv[3]; v4[2]=vv[4]; v4[3]=vv[5];
    } else if (og == 2) {
        v4[4]=vv[0]; v4[5]=vv[1]; v4[6]=vv[2]; v4[7]=vv[3]; v4[8]=vv[4]; v4[9]=vv[5];
    } else {
        v4[10]=vv[0]; v4[11]=vv[1]; v4[12]=vv[2]; v4[13]=vv[3]; v4[14]=vv[4]; v4[15]=vv[5];
    }
}

// MODE 1: per-hash store into acc[h] (no atomics). MODE 0: atomicAdd into one acc.
template<int MODE>
__global__ __launch_bounds__(256, 6) void attn_kernel(
        const float* __restrict__ q, const float* __restrict__ k,
        const float* __restrict__ v, const int* __restrict__ hidx,
        float* __restrict__ acc) {
    __shared__ int list[MAXS];
    __shared__ int scanB[256];
    __shared__ float ks[CH2*KSTR];
    __shared__ float vs[CH2*VSTR];
    int blk = blockIdx.x;
    int qs   = blk % QS;
    int rest = blk / QS;
    int u    = rest % NB;
    int bh   = rest / NB;          // b*NH + h
    int b    = bh / NH;
    int h    = bh - b*NH;
    int tid = threadIdx.x;

    // ---- deterministic ascending bucket list (identical across QS blocks) ----
    const int* hp = &hidx[bh*Ln];
    int hv[16];
    const int4* hp4 = (const int4*)(hp + tid*16);
    #pragma unroll
    for (int t = 0; t < 4; t++) {
        int4 tmp = hp4[t];
        hv[t*4+0]=tmp.x; hv[t*4+1]=tmp.y; hv[t*4+2]=tmp.z; hv[t*4+3]=tmp.w;
    }
    int myCnt = 0;
    #pragma unroll
    for (int t = 0; t < 16; t++) myCnt += (hv[t] == u);
    scanB[tid] = myCnt;
    __syncthreads();
    for (int off = 1; off < 256; off <<= 1) {   // Hillis-Steele inclusive scan
        int vv = (tid >= off) ? scanB[tid - off] : 0;
        __syncthreads();
        scanB[tid] += vv;
        __syncthreads();
    }
    int S = min(scanB[255], MAXS);
    int pos = scanB[tid] - myCnt;               // exclusive prefix
    #pragma unroll
    for (int t = 0; t < 16; t++) {
        if (hv[t] == u) {
            if (pos < MAXS) list[pos] = tid*16 + t;
            pos++;
        }
    }
    __syncthreads();

    // ---- bucketed attention: quad lane c4 owns 16 output channels;
    //      slice qs owns interleaved queries qi = qs + QS*idx (balanced) ----
    int qg = tid >> 2;             // query-group lane (0..63)
    int c4 = tid & 3;              // channel quarter
    for (int p0 = 0; p0*QS*64 < S; p0++) {
        int qi = qs + QS*(p0*64 + qg);
        bool active = qi < S;
        int iq = active ? list[qi] : 0;
        float4 qr0, qr1, qr2, qr3;
        qr0 = qr1 = qr2 = qr3 = make_float4(0.f, 0.f, 0.f, 0.f);
        if (active) {
            const float4* qp = (const float4*)&q[(b*Ln + iq)*CQ];
            qr0 = qp[0]; qr1 = qp[1]; qr2 = qp[2]; qr3 = qp[3];
            // pre-scale by log2(e): exp(s) == exp2(s') with s' = s*log2e
            qr0.x*=LOG2E; qr0.y*=LOG2E; qr0.z*=LOG2E; qr0.w*=LOG2E;
            qr1.x*=LOG2E; qr1.y*=LOG2E; qr1.z*=LOG2E; qr1.w*=LOG2E;
            qr2.x*=LOG2E; qr2.y*=LOG2E; qr2.z*=LOG2E; qr2.w*=LOG2E;
            qr3.x*=LOG2E; qr3.y*=LOG2E; qr3.z*=LOG2E; qr3.w*=LOG2E;
        }
        float lsum = 0.f;
        float4 o0, o1, o2, o3;     // 16 channels per lane
        o0 = o1 = o2 = o3 = make_float4(0.f, 0.f, 0.f, 0.f);

        for (int cc = 0; cc < S; cc += CH2) {
            int nk = min(CH2, S - cc);
            __syncthreads();       // previous chunk fully consumed
            {   // stage K chunk: nk rows x 16 floats, one b128 per thread
                int jj = tid >> 2, cf = tid & 3;
                if (jj < nk) {
                    const float4* kp = (const float4*)&k[(b*Ln + list[cc+jj])*CQ];
                    *(float4*)&ks[jj*KSTR + cf*4] = kp[cf];
                }
            }
            #pragma unroll
            for (int uu = 0; uu < 3; uu++) {   // stage V chunk: nk rows x 64 floats
                int idx = uu*256 + tid;
                int jj = idx >> 4, cf = idx & 15;
                if (jj < nk) {
                    const float4* vp = (const float4*)&v[(b*Ln + list[cc+jj])*Cn];
                    *(float4*)&vs[jj*VSTR + cf*4] = vp[cf];
                }
            }
            __syncthreads();
            if (active) {
                for (int j = 0; j < nk; j++) {
                    const float4* kr = (const float4*)&ks[j*KSTR];   // broadcast
                    float4 k0 = kr[0], k1 = kr[1], k2 = kr[2], k3 = kr[3];
                    // 4 independent partials -> short dependence chains
                    float s0 = qr0.x*k0.x + qr0.y*k0.y + qr0.z*k0.z + qr0.w*k0.w;
                    float s1 = qr1.x*k1.x + qr1.y*k1.y + qr1.z*k1.z + qr1.w*k1.w;
                    float s2 = qr2.x*k2.x + qr2.y*k2.y + qr2.z*k2.z + qr2.w*k2.w;
                    float s3 = qr3.x*k3.x + qr3.y*k3.y + qr3.z*k3.z + qr3.w*k3.w;
                    float sc = (s0 + s1) + (s2 + s3);
                    float pw = exp2f(sc);      // single v_exp_f32
                    lsum += pw;
                    const float4* vp4 = (const float4*)&vs[j*VSTR + c4*16];
                    float4 v0 = vp4[0], v1 = vp4[1], v2 = vp4[2], v3 = vp4[3];
                    o0.x = fmaf(pw, v0.x, o0.x); o0.y = fmaf(pw, v0.y, o0.y);
                    o0.z = fmaf(pw, v0.z, o0.z); o0.w = fmaf(pw, v0.w, o0.w);
                    o1.x = fmaf(pw, v1.x, o1.x); o1.y = fmaf(pw, v1.y, o1.y);
                    o1.z = fmaf(pw, v1.z, o1.z); o1.w = fmaf(pw, v1.w, o1.w);
                    o2.x = fmaf(pw, v2.x, o2.x); o2.y = fmaf(pw, v2.y, o2.y);
                    o2.z = fmaf(pw, v2.z, o2.z); o2.w = fmaf(pw, v2.w, o2.w);
                    o3.x = fmaf(pw, v3.x, o3.x); o3.y = fmaf(pw, v3.y, o3.y);
                    o3.z = fmaf(pw, v3.z, o3.z); o3.w = fmaf(pw, v3.w, o3.w);
                }
            }
        }
        if (active) {
            float inv = 1.f / lsum;   // identical across the quad; no shuffles
            o0.x*=inv; o0.y*=inv; o0.z*=inv; o0.w*=inv;
            o1.x*=inv; o1.y*=inv; o1.z*=inv; o1.w*=inv;
            o2.x*=inv; o2.y*=inv; o2.z*=inv; o2.w*=inv;
            o3.x*=inv; o3.y*=inv; o3.z*=inv; o3.w*=inv;
            if (MODE == 1) {
                float4* ap = (float4*)&acc[((size_t)h*Bn*Ln + b*Ln + iq)*Cn + c4*16];
                ap[0]=o0; ap[1]=o1; ap[2]=o2; ap[3]=o3;
            } else {
                float* ap = &acc[(b*Ln + iq)*Cn + c4*16];
                atomicAdd(&ap[0],  o0.x); atomicAdd(&ap[1],  o0.y);
                atomicAdd(&ap[2],  o0.z); atomicAdd(&ap[3],  o0.w);
                atomicAdd(&ap[4],  o1.x); atomicAdd(&ap[5],  o1.y);
                atomicAdd(&ap[6],  o1.z); atomicAdd(&ap[7],  o1.w);
                atomicAdd(&ap[8],  o2.x); atomicAdd(&ap[9],  o2.y);
                atomicAdd(&ap[10], o2.z); atomicAdd(&ap[11], o2.w);
                atomicAdd(&ap[12], o3.x); atomicAdd(&ap[13], o3.y);
                atomicAdd(&ap[14], o3.z); atomicAdd(&ap[15], o3.w);
            }
        }
    }
}

template<int MODE>
__global__ __launch_bounds__(256) void outconv_kernel(
        const float* __restrict__ acc, const float* __restrict__ Wo,
        const float* __restrict__ bo, const float* __restrict__ gamma,
        const float* __restrict__ x, float* __restrict__ y,
        float* __restrict__ ssum, float* __restrict__ ssq) {
    __shared__ float sWt[Cn*Cn];   // [c][o]
    __shared__ float sb[Cn];
    int tid = threadIdx.x;
    for (int idx = tid; idx < Cn*Cn; idx += 256) {
        int o = idx & 63, c = idx >> 6;
        sWt[c*Cn + o] = Wo[o*Cn + c];
    }
    if (tid < Cn) sb[tid] = bo[tid];
    __syncthreads();
    float g = gamma[0];
    int p = tid & 63, og = tid >> 6;
    int gp = blockIdx.x * 64 + p;
    int b = gp >> 12, l = gp & (Ln - 1);
    int o0 = og * 16;
    float val[16];
    #pragma unroll
    for (int i = 0; i < 16; i++) val[i] = sb[o0 + i];
    const float4* ap0 = (const float4*)&acc[(size_t)gp*Cn];
    #pragma unroll
    for (int c4 = 0; c4 < 16; c4++) {
        float4 t = ap0[c4];
        if (MODE == 1) {
            float4 t1 = ap0[(size_t)ACCSZ/4   + c4];
            float4 t2 = ap0[(size_t)ACCSZ/4*2 + c4];
            float4 t3 = ap0[(size_t)ACCSZ/4*3 + c4];
            t.x += t1.x + t2.x + t3.x; t.y += t1.y + t2.y + t3.y;
            t.z += t1.z + t2.z + t3.z; t.w += t1.w + t2.w + t3.w;
        }
        float a0 = t.x*0.25f, a1 = t.y*0.25f, a2 = t.z*0.25f, a3 = t.w*0.25f;
        const float* w0 = &sWt[(c4*4+0)*Cn + o0];
        const float* w1 = &sWt[(c4*4+1)*Cn + o0];
        const float* w2 = &sWt[(c4*4+2)*Cn + o0];
        const float* w3 = &sWt[(c4*4+3)*Cn + o0];
        #pragma unroll
        for (int i = 0; i < 16; i++) {
            val[i] = fmaf(w0[i], a0, val[i]);
            val[i] = fmaf(w1[i], a1, val[i]);
            val[i] = fmaf(w2[i], a2, val[i]);
            val[i] = fmaf(w3[i], a3, val[i]);
        }
    }
    #pragma unroll
    for (int i = 0; i < 16; i++) {
        int o = o0 + i;
        val[i] = fmaf(g, val[i], x[(b*Cn + o)*Ln + l]);
        y[(b*Cn + o)*Ln + l] = val[i];         // coalesced in p
    }
    // fused batch-stats: per-wave shuffle reduce over the 64 positions
    #pragma unroll
    for (int i = 0; i < 16; i++) {
        float s = val[i], s2 = val[i]*val[i];
        #pragma unroll
        for (int w = 1; w < 64; w <<= 1) {
            s  += __shfl_xor(s,  w, 64);
            s2 += __shfl_xor(s2, w, 64);
        }
        if (p == 0) { atomicAdd(&ssum[o0+i], s); atomicAdd(&ssq[o0+i], s2); }
    }
}

__global__ __launch_bounds__(256) void norm_kernel(
        const float* __restrict__ y,
        const float* __restrict__ ssum, const float* __restrict__ ssq,
        const float* __restrict__ bnw, const float* __restrict__ bnb,
        float* __restrict__ out) {
    int idx = blockIdx.x * 256 + threadIdx.x;  // float4 index
    int flat = idx * 4;
    int c = (flat / Ln) & 63;
    const float n = (float)(Bn*Ln);
    float mu = ssum[c] / n;
    float var = ssq[c] / n - mu*mu;
    float is = rsqrtf(var + EPSV);
    float w = is * bnw[c];
    float bb = bnb[c] - mu * w;
    float4 t = ((const float4*)y)[idx];
    float4 r;
    r.x = t.x*w + bb; r.y = t.y*w + bb; r.z = t.z*w + bb; r.w = t.w*w + bb;
    ((float4*)out)[idx] = r;
}

extern "C" void kernel_launch(void* const* d_in, const int* in_sizes, int n_in,
                              void* d_out, int out_size, void* d_ws, size_t ws_size,
                              hipStream_t stream) {
    const float* x    = (const float*)d_in[0];
    const int*   hidx = (const int*)  d_in[1];
    const float* Wq   = (const float*)d_in[2];
    const float* bq   = (const float*)d_in[3];
    const float* Wk   = (const float*)d_in[4];
    const float* bk   = (const float*)d_in[5];
    const float* Wv   = (const float*)d_in[6];
    const float* bv   = (const float*)d_in[7];
    const float* Wo   = (const float*)d_in[8];
    const float* bo   = (const float*)d_in[9];
    const float* gam  = (const float*)d_in[10];
    const float* bnw  = (const float*)d_in[11];
    const float* bnb  = (const float*)d_in[12];
    float* out = (float*)d_out;

    float* ws  = (float*)d_ws;
    float* q   = ws;
    float* k   = ws + OFF_K;
    float* v   = ws + OFF_V;
    float* acc = ws + OFF_ACC;
    float* y   = ws;            // overlays q/k/v after attn

    const size_t bigNeed = ((size_t)OFF_ACC + 4*(size_t)ACCSZ + 2*Cn) * sizeof(float);
    bool big = ws_size >= bigNeed;
    float* ssum = acc + (big ? 4*(size_t)ACCSZ : (size_t)ACCSZ);
    float* ssq  = ssum + Cn;

    hipMemsetAsync(ssum, 0, 2*Cn*sizeof(float), stream);

    proj_kernel<<<Bn*Ln/64, 256, 0, stream>>>(x, Wq, bq, Wk, bk, Wv, bv, q, k, v);
    if (big) {
        attn_kernel<1><<<Bn*NH*NB*QS, 256, 0, stream>>>(q, k, v, hidx, acc);
        outconv_kernel<1><<<Bn*Ln/64, 256, 0, stream>>>(acc, Wo, bo, gam, x, y, ssum, ssq);
    } else {
        hipMemsetAsync(acc, 0, (size_t)ACCSZ*sizeof(float), stream);
        attn_kernel<0><<<Bn*NH*NB*QS, 256, 0, stream>>>(q, k, v, hidx, acc);
        outconv_kernel<0><<<Bn*Ln/64, 256, 0, stream>>>(acc, Wo, bo, gam, x, y, ssum, ssq);
    }
    norm_kernel<<<Bn*Cn*Ln/4/256, 256, 0, stream>>>(y, ssum, ssq, bnw, bnb, out);
}

// Round 7
// 205.133 us; speedup vs baseline: 1.4158x; 1.4158x over previous
//
#include <hip/hip_runtime.h>
#include <math.h>

#define Bn 4
#define Cn 64
#define Ln 4096
#define CQ 16
#define NH 4
#define NB 32
#define EPSV 1e-5f

#define MAXS 384    // max bucket size (mean 128, sigma ~11 -> impossible to exceed)
#define CH2 64      // staged key chunk
#define QS 4        // query-slice blocks per bucket (interleaved: qi = qs + QS*m)

#define KSTR 20     // ks row stride (floats)
#define VSTR 64     // vs row stride (floats)

#define QSZ   (Bn*Ln*CQ)      // 262144 floats
#define VSZ   (Bn*Ln*Cn)      // 1048576 floats
#define ACCSZ (Bn*Ln*Cn)
#define NBH   (Bn*NH)         // 16
#define GLSZ  (NBH*NB*MAXS)   // 196608 ints

// layout (float units): [q][k][v][glist][gcnt][acc x1|x4][ssum][ssq]
// y overlays q/k/v (dead after attn)
#define OFF_K   QSZ
#define OFF_V   (2*QSZ)
#define OFF_GL  (2*QSZ + VSZ)
#define OFF_GC  (OFF_GL + GLSZ)
#define OFF_ACC (OFF_GC + NBH*NB)

#define LOG2E 1.44269504088896f

__global__ __launch_bounds__(256) void proj_kernel(
        const float* __restrict__ x,
        const float* __restrict__ Wq, const float* __restrict__ bq,
        const float* __restrict__ Wk, const float* __restrict__ bk,
        const float* __restrict__ Wv, const float* __restrict__ bv,
        float* __restrict__ q, float* __restrict__ k, float* __restrict__ v) {
    __shared__ float sWt[Cn*96];   // [c][r]: rows 0-15 Wq, 16-31 Wk, 32-95 Wv
    __shared__ float sb[96];
    int tid = threadIdx.x;
    for (int idx = tid; idx < Cn*96; idx += 256) {
        int r = idx % 96, c = idx / 96;
        float w;
        if (r < 16)      w = Wq[r*Cn + c];
        else if (r < 32) w = Wk[(r-16)*Cn + c];
        else             w = Wv[(r-32)*Cn + c];
        sWt[c*96 + r] = w;
    }
    if (tid < 96) sb[tid] = (tid < 16) ? bq[tid] : (tid < 32 ? bk[tid-16] : bv[tid-32]);
    __syncthreads();
    int p = tid & 63, og = tid >> 6;       // og uniform per wave
    int gp = blockIdx.x * 64 + p;          // flattened position b*L + l
    int b = gp >> 12, l = gp & (Ln - 1);
    const float* xp = &x[b*Cn*Ln + l];
    int r0 = og * 24;
    float val[24];
    #pragma unroll
    for (int i = 0; i < 24; i++) val[i] = sb[r0 + i];
    #pragma unroll
    for (int c0 = 0; c0 < Cn; c0 += 8) {
        float xv[8];
        #pragma unroll
        for (int i = 0; i < 8; i++) xv[i] = xp[(c0 + i)*Ln];   // coalesced in p
        #pragma unroll
        for (int i = 0; i < 8; i++) {
            const float* wrow = &sWt[(c0 + i)*96 + r0];        // LDS broadcast
            #pragma unroll
            for (int j = 0; j < 24; j++) val[j] = fmaf(wrow[j], xv[i], val[j]);
        }
    }
    float4* q4 = (float4*)&q[gp*CQ];
    float4* k4 = (float4*)&k[gp*CQ];
    float4* v4 = (float4*)&v[gp*Cn];
    float4 vv[6];
    #pragma unroll
    for (int i = 0; i < 6; i++)
        vv[i] = make_float4(val[4*i], val[4*i+1], val[4*i+2], val[4*i+3]);
    if (og == 0) {
        q4[0]=vv[0]; q4[1]=vv[1]; q4[2]=vv[2]; q4[3]=vv[3];
        k4[0]=vv[4]; k4[1]=vv[5];
    } else if (og == 1) {
        k4[2]=vv[0]; k4[3]=vv[1];
        v4[0]=vv[2]; v4[1]=vv[3]; v4[2]=vv[4]; v4[3]=vv[5];
    } else if (og == 2) {
        v4[4]=vv[0]; v4[5]=vv[1]; v4[6]=vv[2]; v4[7]=vv[3]; v4[8]=vv[4]; v4[9]=vv[5];
    } else {
        v4[10]=vv[0]; v4[11]=vv[1]; v4[12]=vv[2]; v4[13]=vv[3]; v4[14]=vv[4]; v4[15]=vv[5];
    }
}

// one block per (bh,u): build ascending member list once, to global
__global__ __launch_bounds__(256) void bucketize_kernel(
        const int* __restrict__ hidx, int* __restrict__ glist, int* __restrict__ gcnt) {
    int blk = blockIdx.x;          // = bh*NB + u
    int u  = blk & (NB-1);
    int bh = blk >> 5;
    int tid = threadIdx.x;
    const int4* hp4 = (const int4*)(&hidx[bh*Ln] + tid*16);
    int hv[16];
    #pragma unroll
    for (int t = 0; t < 4; t++) {
        int4 tmp = hp4[t];
        hv[t*4+0]=tmp.x; hv[t*4+1]=tmp.y; hv[t*4+2]=tmp.z; hv[t*4+3]=tmp.w;
    }
    int myCnt = 0;
    #pragma unroll
    for (int t = 0; t < 16; t++) myCnt += (hv[t] == u);
    // wave-level inclusive scan (no barriers)
    int lane = tid & 63, wv = tid >> 6;
    int pre = myCnt;
    #pragma unroll
    for (int d = 1; d < 64; d <<= 1) {
        int t = __shfl_up(pre, d, 64);
        if (lane >= d) pre += t;
    }
    __shared__ int wtot[4];
    if (lane == 63) wtot[wv] = pre;
    __syncthreads();
    int base = 0;
    #pragma unroll
    for (int w = 0; w < 4; w++) base += (w < wv) ? wtot[w] : 0;
    int S = wtot[0] + wtot[1] + wtot[2] + wtot[3];
    int excl = base + pre - myCnt;
    int* gl = &glist[blk*MAXS];
    #pragma unroll
    for (int t = 0; t < 16; t++) {
        if (hv[t] == u) {
            if (excl < MAXS) gl[excl] = tid*16 + t;
            excl++;
        }
    }
    if (tid == 0) gcnt[blk] = min(S, MAXS);
}

// MODE 1: per-hash store into acc[h] (no atomics). MODE 0: atomicAdd into one acc.
template<int MODE>
__global__ __launch_bounds__(256, 2) void attn_kernel(
        const float* __restrict__ q, const float* __restrict__ k,
        const float* __restrict__ v, const int* __restrict__ glist,
        const int* __restrict__ gcnt, float* __restrict__ acc) {
    __shared__ int list[MAXS];
    __shared__ float ks[CH2*KSTR];
    __shared__ float vs[CH2*VSTR];
    int blk = blockIdx.x;
    int qs   = blk % QS;
    int rest = blk / QS;           // = bh*NB + u
    int bh   = rest >> 5;
    int b    = bh / NH;
    int h    = bh - b*NH;
    int tid = threadIdx.x;

    int S = gcnt[rest];
    for (int i = tid; i < S; i += 256) list[i] = glist[rest*MAXS + i];
    __syncthreads();

    // quad lane c4 owns 16 output channels; slice qs owns queries qi = qs + QS*m
    int qg = tid >> 2;             // query-group lane (0..63)
    int c4 = tid & 3;              // channel quarter
    for (int p0 = 0; p0*QS*64 < S; p0++) {
        int qi = qs + QS*(p0*64 + qg);
        bool active = qi < S;
        int iq = active ? list[qi] : 0;
        float4 qr0, qr1, qr2, qr3;
        qr0 = qr1 = qr2 = qr3 = make_float4(0.f, 0.f, 0.f, 0.f);
        if (active) {
            const float4* qp = (const float4*)&q[(b*Ln + iq)*CQ];
            qr0 = qp[0]; qr1 = qp[1]; qr2 = qp[2]; qr3 = qp[3];
            // pre-scale by log2(e): exp(s) == exp2(s * log2e)
            qr0.x*=LOG2E; qr0.y*=LOG2E; qr0.z*=LOG2E; qr0.w*=LOG2E;
            qr1.x*=LOG2E; qr1.y*=LOG2E; qr1.z*=LOG2E; qr1.w*=LOG2E;
            qr2.x*=LOG2E; qr2.y*=LOG2E; qr2.z*=LOG2E; qr2.w*=LOG2E;
            qr3.x*=LOG2E; qr3.y*=LOG2E; qr3.z*=LOG2E; qr3.w*=LOG2E;
        }
        float lsum = 0.f;
        float4 o0, o1, o2, o3;     // 16 channels per lane
        o0 = o1 = o2 = o3 = make_float4(0.f, 0.f, 0.f, 0.f);

        for (int cc = 0; cc < S; cc += CH2) {
            int nk = min(CH2, S - cc);
            __syncthreads();       // previous chunk fully consumed
            {   // stage K chunk: CH2 rows x 16 floats, one b128 per thread
                int jj = tid >> 2, cf = tid & 3;
                if (jj < nk) {
                    const float4* kp = (const float4*)&k[(b*Ln + list[cc+jj])*CQ];
                    *(float4*)&ks[jj*KSTR + cf*4] = kp[cf];
                }
            }
            #pragma unroll
            for (int uu = 0; uu < 4; uu++) {   // stage V chunk: CH2 rows x 64 floats
                int idx = uu*256 + tid;
                int jj = idx >> 4, cf = idx & 15;
                if (jj < nk) {
                    const float4* vp = (const float4*)&v[(b*Ln + list[cc+jj])*Cn];
                    *(float4*)&vs[jj*VSTR + cf*4] = vp[cf];
                }
            }
            __syncthreads();
            if (active) {
                for (int j = 0; j < nk; j++) {
                    const float4* kr = (const float4*)&ks[j*KSTR];   // broadcast
                    float4 k0 = kr[0], k1 = kr[1], k2 = kr[2], k3 = kr[3];
                    float s0 = qr0.x*k0.x + qr0.y*k0.y + qr0.z*k0.z + qr0.w*k0.w;
                    float s1 = qr1.x*k1.x + qr1.y*k1.y + qr1.z*k1.z + qr1.w*k1.w;
                    float s2 = qr2.x*k2.x + qr2.y*k2.y + qr2.z*k2.z + qr2.w*k2.w;
                    float s3 = qr3.x*k3.x + qr3.y*k3.y + qr3.z*k3.z + qr3.w*k3.w;
                    float pw = exp2f((s0 + s1) + (s2 + s3));
                    lsum += pw;
                    const float4* vp4 = (const float4*)&vs[j*VSTR + c4*16];
                    float4 v0 = vp4[0], v1 = vp4[1], v2 = vp4[2], v3 = vp4[3];
                    o0.x = fmaf(pw, v0.x, o0.x); o0.y = fmaf(pw, v0.y, o0.y);
                    o0.z = fmaf(pw, v0.z, o0.z); o0.w = fmaf(pw, v0.w, o0.w);
                    o1.x = fmaf(pw, v1.x, o1.x); o1.y = fmaf(pw, v1.y, o1.y);
                    o1.z = fmaf(pw, v1.z, o1.z); o1.w = fmaf(pw, v1.w, o1.w);
                    o2.x = fmaf(pw, v2.x, o2.x); o2.y = fmaf(pw, v2.y, o2.y);
                    o2.z = fmaf(pw, v2.z, o2.z); o2.w = fmaf(pw, v2.w, o2.w);
                    o3.x = fmaf(pw, v3.x, o3.x); o3.y = fmaf(pw, v3.y, o3.y);
                    o3.z = fmaf(pw, v3.z, o3.z); o3.w = fmaf(pw, v3.w, o3.w);
                }
            }
        }
        if (active) {
            float inv = 1.f / lsum;   // identical across the quad; no shuffles
            o0.x*=inv; o0.y*=inv; o0.z*=inv; o0.w*=inv;
            o1.x*=inv; o1.y*=inv; o1.z*=inv; o1.w*=inv;
            o2.x*=inv; o2.y*=inv; o2.z*=inv; o2.w*=inv;
            o3.x*=inv; o3.y*=inv; o3.z*=inv; o3.w*=inv;
            if (MODE == 1) {
                float4* ap = (float4*)&acc[((size_t)h*Bn*Ln + b*Ln + iq)*Cn + c4*16];
                ap[0]=o0; ap[1]=o1; ap[2]=o2; ap[3]=o3;
            } else {
                float* ap = &acc[(b*Ln + iq)*Cn + c4*16];
                atomicAdd(&ap[0],  o0.x); atomicAdd(&ap[1],  o0.y);
                atomicAdd(&ap[2],  o0.z); atomicAdd(&ap[3],  o0.w);
                atomicAdd(&ap[4],  o1.x); atomicAdd(&ap[5],  o1.y);
                atomicAdd(&ap[6],  o1.z); atomicAdd(&ap[7],  o1.w);
                atomicAdd(&ap[8],  o2.x); atomicAdd(&ap[9],  o2.y);
                atomicAdd(&ap[10], o2.z); atomicAdd(&ap[11], o2.w);
                atomicAdd(&ap[12], o3.x); atomicAdd(&ap[13], o3.y);
                atomicAdd(&ap[14], o3.z); atomicAdd(&ap[15], o3.w);
            }
        }
    }
}

// 512 blocks: (pos-group of 64) x (channel half of 32); wave handles 8 channels
template<int MODE>
__global__ __launch_bounds__(256) void outconv_kernel(
        const float* __restrict__ acc, const float* __restrict__ Wo,
        const float* __restrict__ bo, const float* __restrict__ gamma,
        const float* __restrict__ x, float* __restrict__ y) {
    __shared__ float sWt[Cn*32];   // [c][oo] this half's 32 channels
    __shared__ float sb[32];
    int tid = threadIdx.x;
    int half = blockIdx.x & 1;
    int pg   = blockIdx.x >> 1;
    for (int idx = tid; idx < Cn*32; idx += 256) {
        int oo = idx & 31, c = idx >> 5;
        sWt[c*32 + oo] = Wo[(half*32 + oo)*Cn + c];
    }
    if (tid < 32) sb[tid] = bo[half*32 + tid];
    __syncthreads();
    float g = gamma[0];
    int p = tid & 63, og = tid >> 6;       // wave og: 8 channels
    int gp = pg * 64 + p;
    int b = gp >> 12, l = gp & (Ln - 1);
    int oo0 = og * 8;                      // channel offset within half
    float val[8];
    #pragma unroll
    for (int i = 0; i < 8; i++) val[i] = sb[oo0 + i];
    const float4* ap0 = (const float4*)&acc[(size_t)gp*Cn];
    #pragma unroll
    for (int c4 = 0; c4 < 16; c4++) {
        float4 t = ap0[c4];
        if (MODE == 1) {
            float4 t1 = ap0[(size_t)ACCSZ/4   + c4];
            float4 t2 = ap0[(size_t)ACCSZ/4*2 + c4];
            float4 t3 = ap0[(size_t)ACCSZ/4*3 + c4];
            t.x += t1.x + t2.x + t3.x; t.y += t1.y + t2.y + t3.y;
            t.z += t1.z + t2.z + t3.z; t.w += t1.w + t2.w + t3.w;
        }
        float a0 = t.x*0.25f, a1 = t.y*0.25f, a2 = t.z*0.25f, a3 = t.w*0.25f;
        const float* w0 = &sWt[(c4*4+0)*32 + oo0];
        const float* w1 = &sWt[(c4*4+1)*32 + oo0];
        const float* w2 = &sWt[(c4*4+2)*32 + oo0];
        const float* w3 = &sWt[(c4*4+3)*32 + oo0];
        #pragma unroll
        for (int i = 0; i < 8; i++) {
            val[i] = fmaf(w0[i], a0, val[i]);
            val[i] = fmaf(w1[i], a1, val[i]);
            val[i] = fmaf(w2[i], a2, val[i]);
            val[i] = fmaf(w3[i], a3, val[i]);
        }
    }
    #pragma unroll
    for (int i = 0; i < 8; i++) {
        int o = half*32 + oo0 + i;
        float yv = fmaf(g, val[i], x[(b*Cn + o)*Ln + l]);
        y[(b*Cn + o)*Ln + l] = yv;             // coalesced in p
    }
}

__global__ __launch_bounds__(256) void stats_kernel(
        const float* __restrict__ y, float* __restrict__ ssum, float* __restrict__ ssq) {
    int c = blockIdx.x >> 2;       // channel
    int part = blockIdx.x & 3;     // batch index
    int tid = threadIdx.x;
    const float4* yp = (const float4*)&y[(part*Cn + c)*Ln];
    float s = 0.f, s2 = 0.f;
    #pragma unroll
    for (int i = 0; i < 4; i++) {
        float4 t = yp[i*256 + tid];
        s  += t.x + t.y + t.z + t.w;
        s2 += t.x*t.x + t.y*t.y + t.z*t.z + t.w*t.w;
    }
    #pragma unroll
    for (int w = 1; w < 64; w <<= 1) {
        s  += __shfl_xor(s,  w, 64);
        s2 += __shfl_xor(s2, w, 64);
    }
    __shared__ float rs[4], rs2[4];
    int wv = tid >> 6;
    if ((tid & 63) == 0) { rs[wv] = s; rs2[wv] = s2; }
    __syncthreads();
    if (tid == 0) {
        atomicAdd(&ssum[c], rs[0]+rs[1]+rs[2]+rs[3]);
        atomicAdd(&ssq[c],  rs2[0]+rs2[1]+rs2[2]+rs2[3]);
    }
}

__global__ __launch_bounds__(256) void norm_kernel(
        const float* __restrict__ y,
        const float* __restrict__ ssum, const float* __restrict__ ssq,
        const float* __restrict__ bnw, const float* __restrict__ bnb,
        float* __restrict__ out) {
    int idx = blockIdx.x * 256 + threadIdx.x;  // float4 index
    int flat = idx * 4;
    int c = (flat / Ln) & 63;
    const float n = (float)(Bn*Ln);
    float mu = ssum[c] / n;
    float var = ssq[c] / n - mu*mu;
    float is = rsqrtf(var + EPSV);
    float w = is * bnw[c];
    float bb = bnb[c] - mu * w;
    float4 t = ((const float4*)y)[idx];
    float4 r;
    r.x = t.x*w + bb; r.y = t.y*w + bb; r.z = t.z*w + bb; r.w = t.w*w + bb;
    ((float4*)out)[idx] = r;
}

extern "C" void kernel_launch(void* const* d_in, const int* in_sizes, int n_in,
                              void* d_out, int out_size, void* d_ws, size_t ws_size,
                              hipStream_t stream) {
    const float* x    = (const float*)d_in[0];
    const int*   hidx = (const int*)  d_in[1];
    const float* Wq   = (const float*)d_in[2];
    const float* bq   = (const float*)d_in[3];
    const float* Wk   = (const float*)d_in[4];
    const float* bk   = (const float*)d_in[5];
    const float* Wv   = (const float*)d_in[6];
    const float* bv   = (const float*)d_in[7];
    const float* Wo   = (const float*)d_in[8];
    const float* bo   = (const float*)d_in[9];
    const float* gam  = (const float*)d_in[10];
    const float* bnw  = (const float*)d_in[11];
    const float* bnb  = (const float*)d_in[12];
    float* out = (float*)d_out;

    float* ws    = (float*)d_ws;
    float* q     = ws;
    float* k     = ws + OFF_K;
    float* v     = ws + OFF_V;
    int*   glist = (int*)(ws + OFF_GL);
    int*   gcnt  = (int*)(ws + OFF_GC);
    float* acc   = ws + OFF_ACC;
    float* y     = ws;          // overlays q/k/v after attn

    const size_t bigNeed = ((size_t)OFF_ACC + 4*(size_t)ACCSZ + 2*Cn) * sizeof(float);
    bool big = ws_size >= bigNeed;
    float* ssum = acc + (big ? 4*(size_t)ACCSZ : (size_t)ACCSZ);
    float* ssq  = ssum + Cn;

    hipMemsetAsync(ssum, 0, 2*Cn*sizeof(float), stream);

    bucketize_kernel<<<NBH*NB, 256, 0, stream>>>(hidx, glist, gcnt);
    proj_kernel<<<Bn*Ln/64, 256, 0, stream>>>(x, Wq, bq, Wk, bk, Wv, bv, q, k, v);
    if (big) {
        attn_kernel<1><<<Bn*NH*NB*QS, 256, 0, stream>>>(q, k, v, glist, gcnt, acc);
        outconv_kernel<1><<<Bn*Ln/64*2, 256, 0, stream>>>(acc, Wo, bo, gam, x, y);
    } else {
        hipMemsetAsync(acc, 0, (size_t)ACCSZ*sizeof(float), stream);
        attn_kernel<0><<<Bn*NH*NB*QS, 256, 0, stream>>>(q, k, v, glist, gcnt, acc);
        outconv_kernel<0><<<Bn*Ln/64*2, 256, 0, stream>>>(acc, Wo, bo, gam, x, y);
    }
    stats_kernel<<<Cn*4, 256, 0, stream>>>(y, ssum, ssq);
    norm_kernel<<<Bn*Cn*Ln/4/256, 256, 0, stream>>>(y, ssum, ssq, bnw, bnb, out);
}